// Round 21
// baseline (19.565 us; speedup 1.0000x reference)
//
#include <hip/hip_runtime.h>

#define NQ 8
#define NLAYERS 3

typedef unsigned int uint2ev __attribute__((ext_vector_type(2)));
typedef float f2 __attribute__((ext_vector_type(2)));   // (re, im) or col-pair
typedef __attribute__((address_space(3))) unsigned int lds_u32;
typedef __attribute__((address_space(1))) const unsigned int glb_u32;

// ---- row-local xor exchange (16-lane rows) ----
template<int MASK>
__device__ __forceinline__ float xorlane(float v, int r) {
    if constexpr (MASK == 1) {
        return __int_as_float(__builtin_amdgcn_mov_dpp(__float_as_int(v), 0xB1, 0xF, 0xF, false)); // quad_perm [1,0,3,2]
    } else if constexpr (MASK == 2) {
        return __int_as_float(__builtin_amdgcn_mov_dpp(__float_as_int(v), 0x4E, 0xF, 0xF, false)); // quad_perm [2,3,0,1]
    } else if constexpr (MASK == 4) {
        return __int_as_float(__builtin_amdgcn_ds_swizzle(__float_as_int(v), 0x101F)); // xor4, BitMode
    } else if constexpr (MASK == 8) {
        return __int_as_float(__builtin_amdgcn_mov_dpp(__float_as_int(v), 0x128, 0xF, 0xF, false)); // row_ror:8 == xor 8 in row16
    }
}

template<int MASK>
__device__ __forceinline__ f2 xorlane2(f2 v, int r) {
    f2 o;
    o.x = xorlane<MASK>(v.x, r);
    o.y = xorlane<MASK>(v.y, r);
    return o;
}

// ---- DPP-fused row16 sum; row total lands in lane r=15 of each row ----
template<int CTRL>
__device__ __forceinline__ float dpp_add_stage(float v) {
    int moved = __builtin_amdgcn_update_dpp(0, __float_as_int(v), CTRL, 0xF, 0xF, false);
    return v + __int_as_float(moved);
}
__device__ __forceinline__ float rowsum15(float v) {
    v = dpp_add_stage<0x111>(v);
    v = dpp_add_stage<0x112>(v);
    v = dpp_add_stage<0x114>(v);
    v = dpp_add_stage<0x118>(v);
    return v;
}

// broadcast lane 15 of each row16 to the whole row: src = (lane&0x10)|0x0F
__device__ __forceinline__ float bcast15(float v) {
    return __int_as_float(__builtin_amdgcn_ds_swizzle(__float_as_int(v), 0x1F0));
}

__device__ __forceinline__ f2 cmul(f2 a, f2 b) {
    f2 r;
    r.x = a.x * b.x - a.y * b.y;
    r.y = a.x * b.y + a.y * b.x;
    return r;
}

__device__ __forceinline__ f2 splat(float c) { f2 v; v.x = c; v.y = c; return v; }

template<int Q>
__device__ __forceinline__ void ry16(float c, float s, f2 A[16], int r) {
    f2 vc = splat(c), vs = splat(s);
    if constexpr (Q < 4) {
        constexpr int M = 1 << Q;
#pragma unroll
        for (int j = 0; j < 16; ++j) if (!(j & M)) {
            f2 a0 = A[j], a1 = A[j | M];
            A[j]     = vc * a0 - vs * a1;
            A[j | M] = vs * a0 + vc * a1;
        }
    } else {
        constexpr int LM = 1 << (Q - 4);
        f2 vsg = (r & LM) ? vs : (splat(0.f) - vs);
#pragma unroll
        for (int j = 0; j < 16; ++j) {
            f2 p = xorlane2<LM>(A[j], r);
            A[j] = vc * A[j] + vsg * p;
        }
    }
}

// RY on qubit 7 under the (7,0)-fold relabel: LM=8 exchange crosses the r3
// boundary, so both sides fetch the partner's OTHER register of the local pair.
__device__ __forceinline__ void ry16_q7_relab(float c, float s, f2 A[16], int r) {
    f2 vc = splat(c), vs = splat(s);
    f2 vsg = (r & 8) ? vs : (splat(0.f) - vs);
#pragma unroll
    for (int m = 0; m < 8; ++m) {
        f2 pa = xorlane2<8>(A[2 * m + 1], r);
        f2 pb = xorlane2<8>(A[2 * m],     r);
        A[2 * m]     = vc * A[2 * m]     + vsg * pa;
        A[2 * m + 1] = vc * A[2 * m + 1] + vsg * pb;
    }
}

// ring1: (0,1),(1,2),(2,3) renames; (3,4)..(6,7) one bpermute per register.
// (7,0) folded out (r3 lanes j0-relabeled; compensated downstream).
__device__ __forceinline__ void ring16(f2 A[16], int lane, int r) {
    f2 t;
    t = A[1]; A[1] = A[3]; A[3] = t;
    t = A[5]; A[5] = A[7]; A[7] = t;
    t = A[9]; A[9] = A[11]; A[11] = t;
    t = A[13]; A[13] = A[15]; A[15] = t;
    t = A[2]; A[2] = A[6]; A[6] = t;
    t = A[3]; A[3] = A[7]; A[7] = t;
    t = A[10]; A[10] = A[14]; A[14] = t;
    t = A[11]; A[11] = A[15]; A[15] = t;
    t = A[4]; A[4] = A[12]; A[12] = t;
    t = A[5]; A[5] = A[13]; A[13] = t;
    t = A[6]; A[6] = A[14]; A[14] = t;
    t = A[7]; A[7] = A[15]; A[15] = t;

    int sA = ((lane & 48) | ((r ^ (r << 1)) & 15)) << 2;
    int sB = sA ^ 4;
#pragma unroll
    for (int j = 0; j < 8; ++j) {
        A[j].x = __int_as_float(__builtin_amdgcn_ds_bpermute(sA, __float_as_int(A[j].x)));
        A[j].y = __int_as_float(__builtin_amdgcn_ds_bpermute(sA, __float_as_int(A[j].y)));
    }
#pragma unroll
    for (int j = 8; j < 16; ++j) {
        A[j].x = __int_as_float(__builtin_amdgcn_ds_bpermute(sB, __float_as_int(A[j].x)));
        A[j].y = __int_as_float(__builtin_amdgcn_ds_bpermute(sB, __float_as_int(A[j].y)));
    }
}

// initial-state construction (encode + layer0 fold + ring0 fold), per state
__device__ __forceinline__ void build_state(const float xs[8], const float4* tab,
                                            int r, f2 A[16]) {
    float xmin = xs[0], xmax = xs[0];
#pragma unroll
    for (int q = 1; q < 8; ++q) {
        xmin = fminf(xmin, xs[q]);
        xmax = fmaxf(xmax, xs[q]);
    }
    float inv_pi2 = 1.5707963267948966f / (xmax - xmin + 1e-8f);

    float cc[8], ss[8], cw[8], sw[8];
#pragma unroll
    for (int q = 0; q < 8; ++q) {
        float4 t0 = tab[q];
        float a = fmaf(xs[q] - xmin, inv_pi2, t0.x);
        __sincosf(a, &ss[q], &cc[q]);
        cw[q] = t0.z;
        sw[q] = t0.w;
    }

    int r0v = r & 1, r3v = (r >> 3) & 1;

    f2 X0[2], X1[2], X2[2], X3[2], X4[2];
#pragma unroll
    for (int k = 0; k < 2; ++k) {
        { int b = k ^ r3v; float rr = b ? ss[0] : cc[0];
          X0[k].x = rr * cw[0]; X0[k].y = (b ? rr : -rr) * sw[0]; }
        { int b = k ^ r3v; float rr = b ? ss[1] : cc[1];
          X1[k].x = rr * cw[1]; X1[k].y = (b ? rr : -rr) * sw[1]; }
        { int b = k;        float rr = b ? ss[2] : cc[2];
          X2[k].x = rr * cw[2]; X2[k].y = (b ? rr : -rr) * sw[2]; }
        { int b = k;        float rr = b ? ss[3] : cc[3];
          X3[k].x = rr * cw[3]; X3[k].y = (b ? rr : -rr) * sw[3]; }
        { int b = k ^ r0v;  float rr = b ? ss[4] : cc[4];
          X4[k].x = rr * cw[4]; X4[k].y = (b ? rr : -rr) * sw[4]; }
    }

    f2 pl;
    {
        int b5 = (r ^ (r >> 1)) & 1;
        int b6 = ((r >> 1) ^ (r >> 2)) & 1;
        int b7 = ((r >> 2) ^ (r >> 3)) & 1;
        f2 f5, f6, f7;
        float r5 = b5 ? ss[5] : cc[5];
        f5.x = r5 * cw[5]; f5.y = (b5 ? r5 : -r5) * sw[5];
        float r6 = b6 ? ss[6] : cc[6];
        f6.x = r6 * cw[6]; f6.y = (b6 ? r6 : -r6) * sw[6];
        float r7 = b7 ? ss[7] : cc[7];
        f7.x = r7 * cw[7]; f7.y = (b7 ? r7 : -r7) * sw[7];
        pl = cmul(cmul(f5, f6), f7);
    }

    f2 PP[2][2];
    {
        f2 t0 = cmul(pl, X0[0]);
        f2 t1 = cmul(pl, X0[1]);
        PP[0][0] = cmul(t0, X1[0]);
        PP[0][1] = cmul(t0, X1[1]);
        PP[1][0] = cmul(t1, X1[1]);
        PP[1][1] = cmul(t1, X1[0]);
    }
    f2 Q34[2][2];
    Q34[0][0] = cmul(X3[0], X4[0]);
    Q34[0][1] = cmul(X3[1], X4[1]);
    Q34[1][0] = cmul(X3[1], X4[0]);
    Q34[1][1] = cmul(X3[0], X4[1]);
    f2 R[2][2][2];
#pragma unroll
    for (int j1 = 0; j1 < 2; ++j1)
#pragma unroll
        for (int j2 = 0; j2 < 2; ++j2)
#pragma unroll
            for (int j3 = 0; j3 < 2; ++j3)
                R[j1][j2][j3] = cmul(X2[j1 ^ j2], Q34[j2][j3]);

#pragma unroll
    for (int j3 = 0; j3 < 2; ++j3)
#pragma unroll
        for (int j2 = 0; j2 < 2; ++j2)
#pragma unroll
            for (int j1 = 0; j1 < 2; ++j1)
#pragma unroll
                for (int j0 = 0; j0 < 2; ++j0) {
                    int j = j0 + 2 * j1 + 4 * j2 + 8 * j3;
                    A[j] = cmul(PP[j0][j1], R[j1][j2][j3]);
                }
}

// fused RZ1 product-diagonal, per state
__device__ __forceinline__ void rz1_diag(const float4* tab, int r, f2 A[16]) {
    float4 T12 = tab[12], T13 = tab[13], T14 = tab[14], T15 = tab[15];
    float4 T8 = tab[8], T9 = tab[9], T10 = tab[10], T11 = tab[11];
    f2 L;
    {
        f2 d4, d5, d6, d7;
        d4.x = T12.z; d4.y = (r & 1) ? T12.w : -T12.w;
        d5.x = T13.z; d5.y = (r & 2) ? T13.w : -T13.w;
        d6.x = T14.z; d6.y = (r & 4) ? T14.w : -T14.w;
        d7.x = T15.z; d7.y = (r & 8) ? T15.w : -T15.w;
        L = cmul(cmul(d4, d5), cmul(d6, d7));
    }
    f2 d0n, d0p, d1n, d1p, d2n, d2p, d3n, d3p;
    d0n.x = T8.z;  d0n.y = -T8.w;   d0p.x = T8.z;  d0p.y = T8.w;
    d1n.x = T9.z;  d1n.y = -T9.w;   d1p.x = T9.z;  d1p.y = T9.w;
    d2n.x = T10.z; d2n.y = -T10.w;  d2p.x = T10.z; d2p.y = T10.w;
    d3n.x = T11.z; d3n.y = -T11.w;  d3p.x = T11.z; d3p.y = T11.w;

    f2 t01[4];
    {
        f2 l0 = cmul(L, d0n), l1 = cmul(L, d0p);
        t01[0] = cmul(l0, d1n);
        t01[1] = cmul(l1, d1n);
        t01[2] = cmul(l0, d1p);
        t01[3] = cmul(l1, d1p);
    }
    f2 m23[4];
    m23[0] = cmul(d2n, d3n);
    m23[1] = cmul(d2p, d3n);
    m23[2] = cmul(d2n, d3p);
    m23[3] = cmul(d2p, d3p);

#pragma unroll
    for (int j = 0; j < 16; ++j) {
        f2 D = cmul(t01[j & 3], m23[j >> 2]);
        A[j] = cmul(A[j], D);
    }
}

// measurement -> z[8] (broadcast to all lanes of the row), per state
__device__ __forceinline__ void measure16(const f2 A[16], int r, float z[8]) {
    float P[16];
#pragma unroll
    for (int j = 0; j < 16; ++j) P[j] = A[j].x * A[j].x + A[j].y * A[j].y;

    float Sp[8], Dp[8];
#pragma unroll
    for (int k = 0; k < 8; ++k) {
        Sp[k] = P[2 * k] + P[2 * k + 1];
        Dp[k] = P[2 * k] - P[2 * k + 1];
    }
    float U0 = ((Sp[0] - Sp[1]) - (Sp[2] - Sp[3])) - ((Sp[4] - Sp[5]) - (Sp[6] - Sp[7]));
    float U3 = ((Dp[0] - Dp[1]) - (Dp[2] - Dp[3])) - ((Dp[4] - Dp[5]) - (Dp[6] - Dp[7]));
    float U1 = (Dp[0] - Dp[1]) + (Dp[2] - Dp[3]) + (Dp[4] - Dp[5]) + (Dp[6] - Dp[7]);
    float U2 = ((Dp[0] - Dp[1]) - (Dp[2] - Dp[3])) + ((Dp[4] - Dp[5]) - (Dp[6] - Dp[7]));

    float sg73 = (r & 8) ? -1.f : 1.f;   // (7,0)-fold relabel sign fix
    U1 *= sg73; U2 *= sg73; U3 *= sg73;

    int p1 = r & 1;
    int p2 = (r ^ (r >> 1)) & 1;
    int p3 = (r ^ (r >> 1) ^ (r >> 2)) & 1;
    int p4 = (r ^ (r >> 1) ^ (r >> 2) ^ (r >> 3)) & 1;

    z[0] = bcast15(rowsum15(p4 ? -U0 : U0));
    z[1] = bcast15(rowsum15(U1));
    z[2] = bcast15(rowsum15(U2));
    z[3] = bcast15(rowsum15(U3));
    z[4] = bcast15(rowsum15(p1 ? -U3 : U3));
    z[5] = bcast15(rowsum15(p2 ? -U3 : U3));
    z[6] = bcast15(rowsum15(p3 ? -U3 : U3));
    z[7] = bcast15(rowsum15(p4 ? -U3 : U3));
}

// ============ FUSED: 2 interleaved states/wave (8 samples/wave), 16 samples/block ============
__global__ __launch_bounds__(128) void qfused(
    const float* __restrict__ x,        // [B,8]
    const float* __restrict__ qw,       // [3,8,2]
    const float* __restrict__ W1,       // [8,64]
    const float* __restrict__ b1,       // [64]
    const float* __restrict__ W2,       // [64,256]
    const float* __restrict__ b2,       // [256]
    float* __restrict__ out,            // [B,256]
    int B)
{
    __shared__ float4 tab[NLAYERS * NQ];
    __shared__ float h_lds[16][64];
    __shared__ float w2_lds[64 * 256];  // 64KB

    int tid = threadIdx.x;
    if (tid < NLAYERS * NQ) {
        float w0 = 0.5f * qw[tid * 2 + 0];
        float w1 = 0.5f * qw[tid * 2 + 1];
        if (tid < 8)
            tab[tid] = make_float4(w0, 0.f, __cosf(w1), __sinf(w1));
        else
            tab[tid] = make_float4(__cosf(w0), __sinf(w0), __cosf(w1), __sinf(w1));
    }

    int lane = tid & 63;
    int wid  = tid >> 6;                // 0,1
    int g    = lane >> 4;               // 0..3
    int r    = lane & 15;
    int slA  = wid * 8 + g;             // {0..3, 8..11}
    int slB  = slA + 4;                 // {4..7, 12..15}
    int sbase = blockIdx.x * 16;
    int sampleA = sbase + slA; if (sampleA >= B) sampleA = B - 1;
    int sampleB = sbase + slB; if (sampleB >= B) sampleB = B - 1;

    // x loads first
    const float4* xA4 = (const float4*)(x + sampleA * 8);
    float4 xa0 = xA4[0], xa1 = xA4[1];
    const float4* xB4 = (const float4*)(x + sampleB * 8);
    float4 xb0 = xB4[0], xb1 = xB4[1];

    __syncthreads();   // tab ready

    // async W2 -> LDS staging: 32 rows per wave
#pragma unroll
    for (int k = 0; k < 32; ++k) {
        int row = wid * 32 + k;
        __builtin_amdgcn_global_load_lds(
            (glb_u32*)(W2 + row * 256 + lane * 4),
            (lds_u32*)&w2_lds[row * 256],
            16, 0, 0);
    }

    float xsA[8] = {xa0.x, xa0.y, xa0.z, xa0.w, xa1.x, xa1.y, xa1.z, xa1.w};
    float xsB[8] = {xb0.x, xb0.y, xb0.z, xb0.w, xb1.x, xb1.y, xb1.z, xb1.w};

    // ---- build both states (independent -> ILP) ----
    f2 SA[16], SB[16];
    build_state(xsA, tab, r, SA);
    build_state(xsB, tab, r, SB);

    // ---- layer 1 RY x8, interleaved A/B per gate ----
    {
        float4 t;
        t = tab[8];  ry16<0>(t.x, t.y, SA, r); ry16<0>(t.x, t.y, SB, r);
        t = tab[9];  ry16<1>(t.x, t.y, SA, r); ry16<1>(t.x, t.y, SB, r);
        t = tab[10]; ry16<2>(t.x, t.y, SA, r); ry16<2>(t.x, t.y, SB, r);
        t = tab[11]; ry16<3>(t.x, t.y, SA, r); ry16<3>(t.x, t.y, SB, r);
        t = tab[12]; ry16<4>(t.x, t.y, SA, r); ry16<4>(t.x, t.y, SB, r);
        t = tab[13]; ry16<5>(t.x, t.y, SA, r); ry16<5>(t.x, t.y, SB, r);
        t = tab[14]; ry16<6>(t.x, t.y, SA, r); ry16<6>(t.x, t.y, SB, r);
        t = tab[15]; ry16<7>(t.x, t.y, SA, r); ry16<7>(t.x, t.y, SB, r);
    }

    // ---- fused RZ1 diagonal (per state; diagonal factors shared by compiler CSE) ----
    rz1_diag(tab, r, SA);
    rz1_diag(tab, r, SB);

    // ---- ring 1 (bpermutes pipeline across both states) ----
    ring16(SA, lane, r);
    ring16(SB, lane, r);

    // ---- layer 2 under (7,0)-fold, interleaved ----
    {
        float4 t = tab[16];
        float s0l2 = (r & 8) ? -t.y : t.y;
        ry16<0>(t.x, s0l2, SA, r); ry16<0>(t.x, s0l2, SB, r);
    }
    {
        float4 t;
        t = tab[17]; ry16<1>(t.x, t.y, SA, r); ry16<1>(t.x, t.y, SB, r);
        t = tab[18]; ry16<2>(t.x, t.y, SA, r); ry16<2>(t.x, t.y, SB, r);
        t = tab[19]; ry16<3>(t.x, t.y, SA, r); ry16<3>(t.x, t.y, SB, r);
        t = tab[20]; ry16<4>(t.x, t.y, SA, r); ry16<4>(t.x, t.y, SB, r);
        t = tab[21]; ry16<5>(t.x, t.y, SA, r); ry16<5>(t.x, t.y, SB, r);
        t = tab[22]; ry16<6>(t.x, t.y, SA, r); ry16<6>(t.x, t.y, SB, r);
        t = tab[23]; ry16_q7_relab(t.x, t.y, SA, r); ry16_q7_relab(t.x, t.y, SB, r);
    }

    // ---- measurement (both) ----
    float zA[8], zB[8];
    measure16(SA, r, zA);
    measure16(SB, r, zB);

    // ---- in-wave h for both samples: lane r -> cols r*4..r*4+3 ----
    {
        int c0 = r * 4;
        const float* w1p = W1 + c0;
        f2 aAL = *(const f2*)(b1 + c0);
        f2 aAH = *(const f2*)(b1 + c0 + 2);
        f2 aBL = aAL, aBH = aAH;
#pragma unroll
        for (int q = 0; q < 8; ++q) {
            f2 wL = *(const f2*)(w1p + q * 64);
            f2 wH = *(const f2*)(w1p + q * 64 + 2);
            aAL = aAL + splat(zA[q]) * wL;
            aAH = aAH + splat(zA[q]) * wH;
            aBL = aBL + splat(zB[q]) * wL;
            aBH = aBH + splat(zB[q]) * wH;
        }
        aAL.x = fmaxf(aAL.x, 0.f); aAL.y = fmaxf(aAL.y, 0.f);
        aAH.x = fmaxf(aAH.x, 0.f); aAH.y = fmaxf(aAH.y, 0.f);
        aBL.x = fmaxf(aBL.x, 0.f); aBL.y = fmaxf(aBL.y, 0.f);
        aBH.x = fmaxf(aBH.x, 0.f); aBH.y = fmaxf(aBH.y, 0.f);
        *(float4*)&h_lds[slA][c0] = make_float4(aAL.x, aAL.y, aAH.x, aAH.y);
        *(float4*)&h_lds[slB][c0] = make_float4(aBL.x, aBL.y, aBH.x, aBH.y);
    }
    __syncthreads();   // drains W2 staging + h visible

    // ---- MLP phase 2: 128 threads, 8 samples x 4 cols each; W2 from LDS ----
    int sg = tid >> 6;                  // 0,1
    int c4 = (tid & 63) * 4;
    int sO = sg * 8;
    f2 bbL = *(const f2*)(b2 + c4);
    f2 bbH = *(const f2*)(b2 + c4 + 2);
    f2 aL[8], aH[8];
#pragma unroll
    for (int s = 0; s < 8; ++s) { aL[s] = bbL; aH[s] = bbH; }

#pragma unroll 2
    for (int i4 = 0; i4 < 16; ++i4) {
        const float* wrow = &w2_lds[i4 * 4 * 256 + c4];
        f2 w0L = *(const f2*)(wrow);        f2 w0H = *(const f2*)(wrow + 2);
        f2 w1L = *(const f2*)(wrow + 256);  f2 w1H = *(const f2*)(wrow + 258);
        f2 w2L = *(const f2*)(wrow + 512);  f2 w2H = *(const f2*)(wrow + 514);
        f2 w3L = *(const f2*)(wrow + 768);  f2 w3H = *(const f2*)(wrow + 770);
#pragma unroll
        for (int s = 0; s < 8; ++s) {
            float4 h4 = *(const float4*)&h_lds[sO + s][i4 * 4];
            aL[s] = aL[s] + splat(h4.x) * w0L + splat(h4.y) * w1L + splat(h4.z) * w2L + splat(h4.w) * w3L;
            aH[s] = aH[s] + splat(h4.x) * w0H + splat(h4.y) * w1H + splat(h4.z) * w2H + splat(h4.w) * w3H;
        }
    }

    int srow = sbase + sO;
#pragma unroll
    for (int s = 0; s < 8; ++s) {
        if (srow + s < B)
            *(float4*)(out + (srow + s) * 256 + c4) =
                make_float4(aL[s].x, aL[s].y, aH[s].x, aH[s].y);
    }
}

extern "C" void kernel_launch(void* const* d_in, const int* in_sizes, int n_in,
                              void* d_out, int out_size, void* d_ws, size_t ws_size,
                              hipStream_t stream) {
    const float* x  = (const float*)d_in[0];
    const float* qw = (const float*)d_in[1];
    const float* W1 = (const float*)d_in[2];
    const float* b1 = (const float*)d_in[3];
    const float* W2 = (const float*)d_in[4];
    const float* b2 = (const float*)d_in[5];
    float* out = (float*)d_out;

    int B = in_sizes[0] / NQ;           // 8192

    qfused<<<(B + 15) / 16, 128, 0, stream>>>(x, qw, W1, b1, W2, b2, out, B);
}

// Round 22
// 17.956 us; speedup vs baseline: 1.0896x; 1.0896x over previous
//
#include <hip/hip_runtime.h>

#define NQ 8
#define NLAYERS 3

typedef unsigned int uint2ev __attribute__((ext_vector_type(2)));
typedef float f2 __attribute__((ext_vector_type(2)));   // (re, im) or col-pair
typedef __attribute__((address_space(3))) unsigned int lds_u32;
typedef __attribute__((address_space(1))) const unsigned int glb_u32;

// ---- row-local xor exchange (16-lane rows) ----
template<int MASK>
__device__ __forceinline__ float xorlane(float v, int r) {
    if constexpr (MASK == 1) {
        return __int_as_float(__builtin_amdgcn_mov_dpp(__float_as_int(v), 0xB1, 0xF, 0xF, false)); // quad_perm [1,0,3,2]
    } else if constexpr (MASK == 2) {
        return __int_as_float(__builtin_amdgcn_mov_dpp(__float_as_int(v), 0x4E, 0xF, 0xF, false)); // quad_perm [2,3,0,1]
    } else if constexpr (MASK == 4) {
        return __int_as_float(__builtin_amdgcn_ds_swizzle(__float_as_int(v), 0x101F)); // xor4, BitMode
    } else if constexpr (MASK == 8) {
        return __int_as_float(__builtin_amdgcn_mov_dpp(__float_as_int(v), 0x128, 0xF, 0xF, false)); // row_ror:8 == xor 8 in row16
    }
}

template<int MASK>
__device__ __forceinline__ f2 xorlane2(f2 v, int r) {
    f2 o;
    o.x = xorlane<MASK>(v.x, r);
    o.y = xorlane<MASK>(v.y, r);
    return o;
}

// ---- DPP-fused row16 sum; row total lands in lane r=15 of each row ----
template<int CTRL>
__device__ __forceinline__ float dpp_add_stage(float v) {
    int moved = __builtin_amdgcn_update_dpp(0, __float_as_int(v), CTRL, 0xF, 0xF, false);
    return v + __int_as_float(moved);
}
__device__ __forceinline__ float rowsum15(float v) {
    v = dpp_add_stage<0x111>(v);
    v = dpp_add_stage<0x112>(v);
    v = dpp_add_stage<0x114>(v);
    v = dpp_add_stage<0x118>(v);
    return v;
}

// broadcast lane 15 of each row16 to the whole row: src = (lane&0x10)|0x0F
__device__ __forceinline__ float bcast15(float v) {
    return __int_as_float(__builtin_amdgcn_ds_swizzle(__float_as_int(v), 0x1F0));
}

__device__ __forceinline__ f2 cmul(f2 a, f2 b) {
    f2 r;
    r.x = a.x * b.x - a.y * b.y;
    r.y = a.x * b.y + a.y * b.x;
    return r;
}

__device__ __forceinline__ f2 splat(float c) { f2 v; v.x = c; v.y = c; return v; }

template<int Q>
__device__ __forceinline__ void ry16(float c, float s, f2 A[16], int r) {
    f2 vc = splat(c), vs = splat(s);
    if constexpr (Q < 4) {
        constexpr int M = 1 << Q;
#pragma unroll
        for (int j = 0; j < 16; ++j) if (!(j & M)) {
            f2 a0 = A[j], a1 = A[j | M];
            A[j]     = vc * a0 - vs * a1;
            A[j | M] = vs * a0 + vc * a1;
        }
    } else {
        constexpr int LM = 1 << (Q - 4);
        f2 vsg = (r & LM) ? vs : (splat(0.f) - vs);
#pragma unroll
        for (int j = 0; j < 16; ++j) {
            f2 p = xorlane2<LM>(A[j], r);
            A[j] = vc * A[j] + vsg * p;
        }
    }
}

// RY on qubit 7 when r3=1 lanes are j0-relabeled (post-(7,0)-fold):
// the LM=8 exchange crosses the r3 boundary, so BOTH sides must fetch the
// partner's OTHER register of the local pair (A[j^1]). Buffered per pair to
// avoid read-after-write. Signs unchanged (lane bits are never relabeled).
__device__ __forceinline__ void ry16_q7_relab(float c, float s, f2 A[16], int r) {
    f2 vc = splat(c), vs = splat(s);
    f2 vsg = (r & 8) ? vs : (splat(0.f) - vs);
#pragma unroll
    for (int m = 0; m < 8; ++m) {
        f2 pa = xorlane2<8>(A[2 * m + 1], r);   // partner odd reg -> pairs my even
        f2 pb = xorlane2<8>(A[2 * m],     r);   // partner even reg -> pairs my odd
        A[2 * m]     = vc * A[2 * m]     + vsg * pa;
        A[2 * m + 1] = vc * A[2 * m + 1] + vsg * pb;
    }
}

// ring1: (0,1),(1,2),(2,3) renames; (3,4)..(6,7) one bpermute per register.
// (7,0) is FOLDED OUT: r3 lanes stay j0-relabeled; compensated by
// sign-folded layer-2 RY<0>, cross-register RY<7> (above), and U-sign fix.
__device__ __forceinline__ void ring16(f2 A[16], int lane, int r) {
    f2 t;
    t = A[1]; A[1] = A[3]; A[3] = t;
    t = A[5]; A[5] = A[7]; A[7] = t;
    t = A[9]; A[9] = A[11]; A[11] = t;
    t = A[13]; A[13] = A[15]; A[15] = t;
    t = A[2]; A[2] = A[6]; A[6] = t;
    t = A[3]; A[3] = A[7]; A[7] = t;
    t = A[10]; A[10] = A[14]; A[14] = t;
    t = A[11]; A[11] = A[15]; A[15] = t;
    t = A[4]; A[4] = A[12]; A[12] = t;
    t = A[5]; A[5] = A[13]; A[13] = t;
    t = A[6]; A[6] = A[14]; A[14] = t;
    t = A[7]; A[7] = A[15]; A[15] = t;

    int sA = ((lane & 48) | ((r ^ (r << 1)) & 15)) << 2;
    int sB = sA ^ 4;
#pragma unroll
    for (int j = 0; j < 8; ++j) {
        A[j].x = __int_as_float(__builtin_amdgcn_ds_bpermute(sA, __float_as_int(A[j].x)));
        A[j].y = __int_as_float(__builtin_amdgcn_ds_bpermute(sA, __float_as_int(A[j].y)));
    }
#pragma unroll
    for (int j = 8; j < 16; ++j) {
        A[j].x = __int_as_float(__builtin_amdgcn_ds_bpermute(sB, __float_as_int(A[j].x)));
        A[j].y = __int_as_float(__builtin_amdgcn_ds_bpermute(sB, __float_as_int(A[j].y)));
    }
}

// ============ FUSED: circuit + in-wave h + MLP phase2; 16 samples/block ============
__global__ __launch_bounds__(256) void qfused(
    const float* __restrict__ x,        // [B,8]
    const float* __restrict__ qw,       // [3,8,2]
    const float* __restrict__ W1,       // [8,64]
    const float* __restrict__ b1,       // [64]
    const float* __restrict__ W2,       // [64,256]
    const float* __restrict__ b2,       // [256]
    float* __restrict__ out,            // [B,256]
    int B)
{
    __shared__ float4 tab[NLAYERS * NQ];
    __shared__ float h_lds[16][64];
    __shared__ float w2_lds[64 * 256];  // 64KB

    int tid = threadIdx.x;
    if (tid < NLAYERS * NQ) {
        float w0 = 0.5f * qw[tid * 2 + 0];
        float w1 = 0.5f * qw[tid * 2 + 1];
        if (tid < 8)
            tab[tid] = make_float4(w0, 0.f, __cosf(w1), __sinf(w1));
        else
            tab[tid] = make_float4(__cosf(w0), __sinf(w0), __cosf(w1), __sinf(w1));
    }

    int lane = tid & 63;
    int wid  = tid >> 6;
    int g    = lane >> 4;
    int r    = lane & 15;
    int sl   = wid * 4 + g;             // sample slot 0..15
    int sbase = blockIdx.x * 16;
    int sample = sbase + sl;
    if (sample >= B) sample = B - 1;

    // x load first (keeps its wait off the staging queue)
    const float4* x4 = (const float4*)(x + sample * 8);
    float4 xa = x4[0], xb = x4[1];

    __syncthreads();   // tab ready

    // async W2 -> LDS staging; hides under the circuit
#pragma unroll
    for (int k = 0; k < 16; ++k) {
        int row = wid * 16 + k;
        __builtin_amdgcn_global_load_lds(
            (glb_u32*)(W2 + row * 256 + lane * 4),
            (lds_u32*)&w2_lds[row * 256],
            16, 0, 0);
    }

    float xs[8] = {xa.x, xa.y, xa.z, xa.w, xb.x, xb.y, xb.z, xb.w};
    float xmin = xs[0], xmax = xs[0];
#pragma unroll
    for (int q = 1; q < 8; ++q) {
        xmin = fminf(xmin, xs[q]);
        xmax = fmaxf(xmax, xs[q]);
    }
    float inv_pi2 = 1.5707963267948966f / (xmax - xmin + 1e-8f);

    float4 T8 = tab[8],  T9 = tab[9],  T10 = tab[10], T11 = tab[11];
    float4 T12 = tab[12], T13 = tab[13], T14 = tab[14], T15 = tab[15];
    float4 T16 = tab[16], T17 = tab[17], T18 = tab[18], T19 = tab[19];
    float4 T20 = tab[20], T21 = tab[21], T22 = tab[22], T23 = tab[23];

    float cc[8], ss[8], cw[8], sw[8];
#pragma unroll
    for (int q = 0; q < 8; ++q) {
        float4 t0 = tab[q];
        float a = fmaf(xs[q] - xmin, inv_pi2, t0.x);
        __sincosf(a, &ss[q], &cc[q]);
        cw[q] = t0.z;
        sw[q] = t0.w;
    }

    int r0v = r & 1, r3v = (r >> 3) & 1;

    f2 X0[2], X1[2], X2[2], X3[2], X4[2];
#pragma unroll
    for (int k = 0; k < 2; ++k) {
        { int b = k ^ r3v; float rr = b ? ss[0] : cc[0];
          X0[k].x = rr * cw[0]; X0[k].y = (b ? rr : -rr) * sw[0]; }
        { int b = k ^ r3v; float rr = b ? ss[1] : cc[1];
          X1[k].x = rr * cw[1]; X1[k].y = (b ? rr : -rr) * sw[1]; }
        { int b = k;        float rr = b ? ss[2] : cc[2];
          X2[k].x = rr * cw[2]; X2[k].y = (b ? rr : -rr) * sw[2]; }
        { int b = k;        float rr = b ? ss[3] : cc[3];
          X3[k].x = rr * cw[3]; X3[k].y = (b ? rr : -rr) * sw[3]; }
        { int b = k ^ r0v;  float rr = b ? ss[4] : cc[4];
          X4[k].x = rr * cw[4]; X4[k].y = (b ? rr : -rr) * sw[4]; }
    }

    f2 pl;
    {
        int b5 = (r ^ (r >> 1)) & 1;
        int b6 = ((r >> 1) ^ (r >> 2)) & 1;
        int b7 = ((r >> 2) ^ (r >> 3)) & 1;
        f2 f5, f6, f7;
        float r5 = b5 ? ss[5] : cc[5];
        f5.x = r5 * cw[5]; f5.y = (b5 ? r5 : -r5) * sw[5];
        float r6 = b6 ? ss[6] : cc[6];
        f6.x = r6 * cw[6]; f6.y = (b6 ? r6 : -r6) * sw[6];
        float r7 = b7 ? ss[7] : cc[7];
        f7.x = r7 * cw[7]; f7.y = (b7 ? r7 : -r7) * sw[7];
        pl = cmul(cmul(f5, f6), f7);
    }

    f2 PP[2][2];
    {
        f2 t0 = cmul(pl, X0[0]);
        f2 t1 = cmul(pl, X0[1]);
        PP[0][0] = cmul(t0, X1[0]);
        PP[0][1] = cmul(t0, X1[1]);
        PP[1][0] = cmul(t1, X1[1]);
        PP[1][1] = cmul(t1, X1[0]);
    }
    f2 Q34[2][2];
    Q34[0][0] = cmul(X3[0], X4[0]);
    Q34[0][1] = cmul(X3[1], X4[1]);
    Q34[1][0] = cmul(X3[1], X4[0]);
    Q34[1][1] = cmul(X3[0], X4[1]);
    f2 R[2][2][2];
#pragma unroll
    for (int j1 = 0; j1 < 2; ++j1)
#pragma unroll
        for (int j2 = 0; j2 < 2; ++j2)
#pragma unroll
            for (int j3 = 0; j3 < 2; ++j3)
                R[j1][j2][j3] = cmul(X2[j1 ^ j2], Q34[j2][j3]);

    f2 A[16];
#pragma unroll
    for (int j3 = 0; j3 < 2; ++j3)
#pragma unroll
        for (int j2 = 0; j2 < 2; ++j2)
#pragma unroll
            for (int j1 = 0; j1 < 2; ++j1)
#pragma unroll
                for (int j0 = 0; j0 < 2; ++j0) {
                    int j = j0 + 2 * j1 + 4 * j2 + 8 * j3;
                    A[j] = cmul(PP[j0][j1], R[j1][j2][j3]);
                }

    ry16<0>(T8.x,  T8.y,  A, r);
    ry16<1>(T9.x,  T9.y,  A, r);
    ry16<2>(T10.x, T10.y, A, r);
    ry16<3>(T11.x, T11.y, A, r);
    ry16<4>(T12.x, T12.y, A, r);
    ry16<5>(T13.x, T13.y, A, r);
    ry16<6>(T14.x, T14.y, A, r);
    ry16<7>(T15.x, T15.y, A, r);

    {
        f2 L;
        {
            f2 d4, d5, d6, d7;
            d4.x = T12.z; d4.y = (r & 1) ? T12.w : -T12.w;
            d5.x = T13.z; d5.y = (r & 2) ? T13.w : -T13.w;
            d6.x = T14.z; d6.y = (r & 4) ? T14.w : -T14.w;
            d7.x = T15.z; d7.y = (r & 8) ? T15.w : -T15.w;
            L = cmul(cmul(d4, d5), cmul(d6, d7));
        }
        f2 d0n, d0p, d1n, d1p, d2n, d2p, d3n, d3p;
        d0n.x = T8.z;  d0n.y = -T8.w;   d0p.x = T8.z;  d0p.y = T8.w;
        d1n.x = T9.z;  d1n.y = -T9.w;   d1p.x = T9.z;  d1p.y = T9.w;
        d2n.x = T10.z; d2n.y = -T10.w;  d2p.x = T10.z; d2p.y = T10.w;
        d3n.x = T11.z; d3n.y = -T11.w;  d3p.x = T11.z; d3p.y = T11.w;

        f2 t01[4];
        {
            f2 l0 = cmul(L, d0n), l1 = cmul(L, d0p);
            t01[0] = cmul(l0, d1n);
            t01[1] = cmul(l1, d1n);
            t01[2] = cmul(l0, d1p);
            t01[3] = cmul(l1, d1p);
        }
        f2 m23[4];
        m23[0] = cmul(d2n, d3n);
        m23[1] = cmul(d2p, d3n);
        m23[2] = cmul(d2n, d3p);
        m23[3] = cmul(d2p, d3p);

#pragma unroll
        for (int j = 0; j < 16; ++j) {
            f2 D = cmul(t01[j & 3], m23[j >> 2]);
            A[j] = cmul(A[j], D);
        }
    }

    ring16(A, lane, r);

    // layer 2 under (7,0)-fold:
    // RY<0>: X-conjugated for r3 lanes (s -> -s)
    {
        float s0l2 = (r & 8) ? -T16.y : T16.y;
        ry16<0>(T16.x, s0l2, A, r);
    }
    ry16<1>(T17.x, T17.y, A, r);
    ry16<2>(T18.x, T18.y, A, r);
    ry16<3>(T19.x, T19.y, A, r);
    ry16<4>(T20.x, T20.y, A, r);
    ry16<5>(T21.x, T21.y, A, r);
    ry16<6>(T22.x, T22.y, A, r);
    // RY<7>: crosses the r3 boundary -> cross-register exchange variant
    ry16_q7_relab(T23.x, T23.y, A, r);

    // ---- measurement (registers j0-relabeled for r3 lanes) ----
    float P[16];
#pragma unroll
    for (int j = 0; j < 16; ++j) P[j] = A[j].x * A[j].x + A[j].y * A[j].y;

    float Sp[8], Dp[8];
#pragma unroll
    for (int k = 0; k < 8; ++k) {
        Sp[k] = P[2 * k] + P[2 * k + 1];
        Dp[k] = P[2 * k] - P[2 * k + 1];
    }
    float U0 = ((Sp[0] - Sp[1]) - (Sp[2] - Sp[3])) - ((Sp[4] - Sp[5]) - (Sp[6] - Sp[7]));
    float U3 = ((Dp[0] - Dp[1]) - (Dp[2] - Dp[3])) - ((Dp[4] - Dp[5]) - (Dp[6] - Dp[7]));
    float U1 = (Dp[0] - Dp[1]) + (Dp[2] - Dp[3]) + (Dp[4] - Dp[5]) + (Dp[6] - Dp[7]);
    float U2 = ((Dp[0] - Dp[1]) - (Dp[2] - Dp[3])) + ((Dp[4] - Dp[5]) - (Dp[6] - Dp[7]));

    // relabel sign fix: Dp-based U's negate for r3 lanes; Sp-based U0 invariant
    {
        float sg73 = (r & 8) ? -1.f : 1.f;
        U1 *= sg73; U2 *= sg73; U3 *= sg73;
    }

    int p1 = r & 1;
    int p2 = (r ^ (r >> 1)) & 1;
    int p3 = (r ^ (r >> 1) ^ (r >> 2)) & 1;
    int p4 = (r ^ (r >> 1) ^ (r >> 2) ^ (r >> 3)) & 1;

    float z0 = bcast15(rowsum15(p4 ? -U0 : U0));
    float z1 = bcast15(rowsum15(U1));
    float z2 = bcast15(rowsum15(U2));
    float z3 = bcast15(rowsum15(U3));
    float z4 = bcast15(rowsum15(p1 ? -U3 : U3));
    float z5 = bcast15(rowsum15(p2 ? -U3 : U3));
    float z6 = bcast15(rowsum15(p3 ? -U3 : U3));
    float z7 = bcast15(rowsum15(p4 ? -U3 : U3));

    // ---- in-wave h: lane r computes cols r*4..r*4+3 (f2-packed FMAs) ----
    {
        int c0 = r * 4;
        f2 accL = *(const f2*)(b1 + c0);
        f2 accH = *(const f2*)(b1 + c0 + 2);
        const float* w1p = W1 + c0;
        float zq[8] = {z0, z1, z2, z3, z4, z5, z6, z7};
#pragma unroll
        for (int q = 0; q < 8; ++q) {
            f2 wL = *(const f2*)(w1p + q * 64);
            f2 wH = *(const f2*)(w1p + q * 64 + 2);
            f2 zz = splat(zq[q]);
            accL = accL + zz * wL;
            accH = accH + zz * wH;
        }
        accL.x = fmaxf(accL.x, 0.f); accL.y = fmaxf(accL.y, 0.f);
        accH.x = fmaxf(accH.x, 0.f); accH.y = fmaxf(accH.y, 0.f);
        *(float4*)&h_lds[sl][c0] = make_float4(accL.x, accL.y, accH.x, accH.y);
    }
    __syncthreads();   // drains W2 staging + h visible

    // ---- MLP phase 2: 4 samples x 4 cols per thread; W2 from LDS; f2-packed ----
    int sg = tid >> 6;
    int c4 = (tid & 63) * 4;
    f2 bbL = *(const f2*)(b2 + c4);
    f2 bbH = *(const f2*)(b2 + c4 + 2);
    f2 a0L = bbL, a0H = bbH, a1L = bbL, a1H = bbH;
    f2 a2L = bbL, a2H = bbH, a3L = bbL, a3H = bbH;
    const int sO = sg * 4;

#pragma unroll 2
    for (int i4 = 0; i4 < 16; ++i4) {
        const float* wrow = &w2_lds[i4 * 4 * 256 + c4];
        f2 w0L = *(const f2*)(wrow);        f2 w0H = *(const f2*)(wrow + 2);
        f2 w1L = *(const f2*)(wrow + 256);  f2 w1H = *(const f2*)(wrow + 258);
        f2 w2L = *(const f2*)(wrow + 512);  f2 w2H = *(const f2*)(wrow + 514);
        f2 w3L = *(const f2*)(wrow + 768);  f2 w3H = *(const f2*)(wrow + 770);
        float4 h0 = *(const float4*)&h_lds[sO + 0][i4 * 4];
        float4 h1 = *(const float4*)&h_lds[sO + 1][i4 * 4];
        float4 h2 = *(const float4*)&h_lds[sO + 2][i4 * 4];
        float4 h3 = *(const float4*)&h_lds[sO + 3][i4 * 4];

        a0L = a0L + splat(h0.x) * w0L + splat(h0.y) * w1L + splat(h0.z) * w2L + splat(h0.w) * w3L;
        a0H = a0H + splat(h0.x) * w0H + splat(h0.y) * w1H + splat(h0.z) * w2H + splat(h0.w) * w3H;
        a1L = a1L + splat(h1.x) * w0L + splat(h1.y) * w1L + splat(h1.z) * w2L + splat(h1.w) * w3L;
        a1H = a1H + splat(h1.x) * w0H + splat(h1.y) * w1H + splat(h1.z) * w2H + splat(h1.w) * w3H;
        a2L = a2L + splat(h2.x) * w0L + splat(h2.y) * w1L + splat(h2.z) * w2L + splat(h2.w) * w3L;
        a2H = a2H + splat(h2.x) * w0H + splat(h2.y) * w1H + splat(h2.z) * w2H + splat(h2.w) * w3H;
        a3L = a3L + splat(h3.x) * w0L + splat(h3.y) * w1L + splat(h3.z) * w2L + splat(h3.w) * w3L;
        a3H = a3H + splat(h3.x) * w0H + splat(h3.y) * w1H + splat(h3.z) * w2H + splat(h3.w) * w3H;
    }

    int srow = sbase + sO;
    if (srow + 0 < B) *(float4*)(out + (srow + 0) * 256 + c4) = make_float4(a0L.x, a0L.y, a0H.x, a0H.y);
    if (srow + 1 < B) *(float4*)(out + (srow + 1) * 256 + c4) = make_float4(a1L.x, a1L.y, a1H.x, a1H.y);
    if (srow + 2 < B) *(float4*)(out + (srow + 2) * 256 + c4) = make_float4(a2L.x, a2L.y, a2H.x, a2H.y);
    if (srow + 3 < B) *(float4*)(out + (srow + 3) * 256 + c4) = make_float4(a3L.x, a3L.y, a3H.x, a3H.y);
}

extern "C" void kernel_launch(void* const* d_in, const int* in_sizes, int n_in,
                              void* d_out, int out_size, void* d_ws, size_t ws_size,
                              hipStream_t stream) {
    const float* x  = (const float*)d_in[0];
    const float* qw = (const float*)d_in[1];
    const float* W1 = (const float*)d_in[2];
    const float* b1 = (const float*)d_in[3];
    const float* W2 = (const float*)d_in[4];
    const float* b2 = (const float*)d_in[5];
    float* out = (float*)d_out;

    int B = in_sizes[0] / NQ;           // 8192

    qfused<<<(B + 15) / 16, 256, 0, stream>>>(x, qw, W1, b1, W2, b2, out, B);
}